// Round 8
// baseline (131.780 us; speedup 1.0000x reference)
//
#include <hip/hip_runtime.h>
#include <hip/hip_bf16.h>

// ModulatedLinear: B=4, S=4096, IN=OUT=MOD=512
// out[t,o] = demod[t,o] * sum_i W[o,i]*s[t,i]*x[t,i] + bias[o]
//   s[t,i]    = sum_m mod[t,m]*mod_w[i,m] + mod_b[i]
//   demod[t,o]= rsqrt(sum_i (W[o,i]*s[t,i])^2 + 1e-8)
//
// bf16 MFMA pipeline:
//  K0: fp32->bf16 converts
//  K1: s = modb @ mod_wb^T; LDS-transpose epilogue -> xs, ss (proven)
//  K2: dual GEMM 128x128, BK=32 SINGLE-buffered (dbuf reverted: R5-R7 showed
//      concurrent DMA-write || ds_read = 1.34e7 bank conflicts, invariant to
//      all static-pattern fixes), 32KB LDS -> 4 blocks/CU for latency hiding.

#define T_TOK 16384
#define DIM 512

typedef __attribute__((ext_vector_type(4))) float f32x4;
typedef __attribute__((ext_vector_type(8))) short bf16x8;

static __device__ __forceinline__ unsigned short f2bf(float f) {
    union { float f; unsigned int u; } v; v.f = f;
    unsigned int u = v.u;
    u += 0x7fffu + ((u >> 16) & 1u);   // RNE
    return (unsigned short)(u >> 16);
}
static __device__ __forceinline__ float bf2f(unsigned short h) {
    union { unsigned int u; float f; } v; v.u = ((unsigned int)h) << 16;
    return v.f;
}

// ---------------- K0: converts ----------------
__global__ __launch_bounds__(256) void k0_convert(
    const float* __restrict__ mod, const float* __restrict__ weight,
    const float* __restrict__ mod_w,
    unsigned short* __restrict__ modb, unsigned short* __restrict__ Wb,
    unsigned short* __restrict__ W2b, unsigned short* __restrict__ mwb)
{
    const int NV_MOD = (T_TOK * DIM) / 4;
    const int NV_W   = (DIM * DIM) / 4;
    int idx = blockIdx.x * blockDim.x + threadIdx.x;
    int stride = gridDim.x * blockDim.x;
    for (int i = idx; i < NV_MOD; i += stride) {
        f32x4 v = ((const f32x4*)mod)[i];
        ushort4 o; o.x = f2bf(v[0]); o.y = f2bf(v[1]); o.z = f2bf(v[2]); o.w = f2bf(v[3]);
        ((ushort4*)modb)[i] = o;
    }
    for (int i = idx; i < NV_W; i += stride) {
        f32x4 v = ((const f32x4*)weight)[i];
        ushort4 o;  o.x = f2bf(v[0]); o.y = f2bf(v[1]); o.z = f2bf(v[2]); o.w = f2bf(v[3]);
        ((ushort4*)Wb)[i] = o;
        ushort4 o2; o2.x = f2bf(v[0]*v[0]); o2.y = f2bf(v[1]*v[1]);
                    o2.z = f2bf(v[2]*v[2]); o2.w = f2bf(v[3]*v[3]);
        ((ushort4*)W2b)[i] = o2;
        f32x4 m = ((const f32x4*)mod_w)[i];
        ushort4 o3; o3.x = f2bf(m[0]); o3.y = f2bf(m[1]); o3.z = f2bf(m[2]); o3.w = f2bf(m[3]);
        ((ushort4*)mwb)[i] = o3;
    }
}

// ---------------- K1: s-GEMM + LDS-transpose epilogue (unchanged) ----------------
__global__ __launch_bounds__(256, 2) void k1_style(
    const unsigned short* __restrict__ modb,   // [T][512] bf16
    const unsigned short* __restrict__ mwb,    // [512][512] bf16 (IN x MOD)
    const float* __restrict__ x,               // [T][512] fp32
    const float* __restrict__ mod_b,           // [512]
    unsigned short* __restrict__ xs,           // [T][512] bf16 out
    unsigned short* __restrict__ ss)           // [T][512] bf16 out
{
    __shared__ union {
        struct { unsigned short A[128 * 64]; unsigned short B[128 * 64]; } stg;
        unsigned short str[128 * 144];
    } u;
    const int tid  = threadIdx.x;
    const int lane = tid & 63;
    const int w    = tid >> 6;
    const int wr   = w >> 1, wc = w & 1;
    const int nbn  = DIM / 128;
    const int bm   = blockIdx.x / nbn;
    const int bn   = blockIdx.x % nbn;

    const int srow  = lane >> 3;
    const int lslot = (lane & 7) ^ srow;
    const int fr    = lane & 15;
    const int fs    = lane >> 4;

    f32x4 acc[4][4] = {};

    const size_t aBase = (size_t)bm * 128 * DIM;
    const size_t bBase = (size_t)bn * 128 * DIM;

    for (int kb = 0; kb < DIM; kb += 64) {
#pragma unroll
        for (int q = 0; q < 4; ++q) {
            int row = w * 32 + q * 8 + srow;
            const unsigned short* ga = modb + aBase + (size_t)row * DIM + kb + lslot * 8;
            const unsigned short* gb = mwb  + bBase + (size_t)row * DIM + kb + lslot * 8;
            __builtin_amdgcn_global_load_lds(
                (__attribute__((address_space(1))) void*)ga,
                (__attribute__((address_space(3))) void*)(u.stg.A + w * 2048 + q * 512), 16, 0, 0);
            __builtin_amdgcn_global_load_lds(
                (__attribute__((address_space(1))) void*)gb,
                (__attribute__((address_space(3))) void*)(u.stg.B + w * 2048 + q * 512), 16, 0, 0);
        }
        __syncthreads();
#pragma unroll
        for (int kk = 0; kk < 64; kk += 32) {
            bf16x8 af[4], bfv[4];
#pragma unroll
            for (int mi = 0; mi < 4; ++mi) {
                int row = wr * 64 + mi * 16 + fr;
                int ps  = ((kk >> 3) + fs) ^ (fr & 7);
                af[mi] = *(const bf16x8*)(u.stg.A + row * 64 + ps * 8);
            }
#pragma unroll
            for (int ni = 0; ni < 4; ++ni) {
                int row = wc * 64 + ni * 16 + fr;
                int ps  = ((kk >> 3) + fs) ^ (fr & 7);
                bfv[ni] = *(const bf16x8*)(u.stg.B + row * 64 + ps * 8);
            }
#pragma unroll
            for (int mi = 0; mi < 4; ++mi)
#pragma unroll
                for (int ni = 0; ni < 4; ++ni)
                    acc[mi][ni] = __builtin_amdgcn_mfma_f32_16x16x32_bf16(
                        af[mi], bfv[ni], acc[mi][ni], 0, 0, 0);
        }
        __syncthreads();
    }

#pragma unroll
    for (int ni = 0; ni < 4; ++ni) {
        int col = wc * 64 + ni * 16 + fr;
        float mb = mod_b[bn * 128 + col];
#pragma unroll
        for (int mi = 0; mi < 4; ++mi) {
#pragma unroll
            for (int j = 0; j < 4; ++j) {
                int row = wr * 64 + mi * 16 + fs * 4 + j;
                u.str[row * 144 + col] = f2bf(acc[mi][ni][j] + mb);
            }
        }
    }
    __syncthreads();
#pragma unroll
    for (int q = 0; q < 8; ++q) {
        int row = w * 32 + q * 4 + (lane >> 4);
        int c8  = (lane & 15) * 8;
        bf16x8 s8 = *(const bf16x8*)(u.str + row * 144 + c8);
        size_t off = ((size_t)bm * 128 + row) * DIM + bn * 128 + c8;
        f32x4 x0 = *(const f32x4*)(x + off);
        f32x4 x1 = *(const f32x4*)(x + off + 4);
        bf16x8 xsv, ssv;
#pragma unroll
        for (int e = 0; e < 8; ++e) {
            float sf = bf2f((unsigned short)s8[e]);
            float xv = (e < 4) ? x0[e] : x1[e - 4];
            xsv[e] = (short)f2bf(xv * sf);
            ssv[e] = (short)f2bf(sf * sf);
        }
        *(bf16x8*)(xs + off) = xsv;
        *(bf16x8*)(ss + off) = ssv;
    }
}

// ---------------- K2: dual GEMM 128x128, BK=32 single-buffered, 4 blk/CU ----
// LDS tiles [128 rows][32 cols] bf16 = 8KB/stream; phys 16B-slot =
// logical ^ ((row>>1)&3) -> uniform 8 lanes/quad on ds_read_b128 AND on the
// (linear) DMA write. STAGE and COMPUTE are barrier-separated (no concurrent
// DMA-write||ds_read on the same LDS -> no arbitration conflicts).
__global__ __launch_bounds__(256, 4) void k2_main(
    const unsigned short* __restrict__ xs,   // [T][512] bf16
    const unsigned short* __restrict__ ss,   // [T][512] bf16
    const unsigned short* __restrict__ Wb,   // [512][512] bf16 (OUT x IN)
    const unsigned short* __restrict__ W2b,  // [512][512] bf16
    const float* __restrict__ bias,          // [512]
    float* __restrict__ out)                 // [T][512] fp32
{
    __shared__ unsigned short stg[4][128 * 32];   // 32KB total
    const int tid  = threadIdx.x;
    const int lane = tid & 63;
    const int w    = tid >> 6;
    const int wr   = w >> 1, wc = w & 1;
    // XCD-chunked bijective swizzle (512 blocks, 64/XCD)
    const int tile = (blockIdx.x & 7) * 64 + (blockIdx.x >> 3);
    const int bm   = tile >> 2;
    const int bn   = tile & 3;

    const int fr = lane & 15;
    const int fs = lane >> 4;

    f32x4 a1[4][4] = {};
    f32x4 a2[4][4] = {};

    const size_t aBase = (size_t)bm * 128 * DIM;
    const size_t bBase = (size_t)bn * 128 * DIM;

    // staging: one wave-issue = 1KB = 16 rows x 4 slots
    const int srw = lane >> 2;             // row within issue
    const int sp  = lane & 3;              // phys slot written by this lane

    for (int kb = 0; kb < DIM; kb += 32) {
#pragma unroll
        for (int q = 0; q < 2; ++q) {
            int rb   = w * 32 + q * 16;
            int row  = rb + srw;
            int slog = sp ^ ((row >> 1) & 3);   // involutive swizzle
            size_t gA = aBase + (size_t)row * DIM + kb + slog * 8;
            size_t gB = bBase + (size_t)row * DIM + kb + slog * 8;
            __builtin_amdgcn_global_load_lds(
                (__attribute__((address_space(1))) void*)(xs + gA),
                (__attribute__((address_space(3))) void*)(stg[0] + rb * 32), 16, 0, 0);
            __builtin_amdgcn_global_load_lds(
                (__attribute__((address_space(1))) void*)(ss + gA),
                (__attribute__((address_space(3))) void*)(stg[1] + rb * 32), 16, 0, 0);
            __builtin_amdgcn_global_load_lds(
                (__attribute__((address_space(1))) void*)(Wb + gB),
                (__attribute__((address_space(3))) void*)(stg[2] + rb * 32), 16, 0, 0);
            __builtin_amdgcn_global_load_lds(
                (__attribute__((address_space(1))) void*)(W2b + gB),
                (__attribute__((address_space(3))) void*)(stg[3] + rb * 32), 16, 0, 0);
        }
        __syncthreads();

        bf16x8 axs[4], ass[4], bw[4], bw2[4];
#pragma unroll
        for (int mi = 0; mi < 4; ++mi) {
            int row = wr * 64 + mi * 16 + fr;
            int off = row * 32 + ((fs ^ ((row >> 1) & 3)) * 8);
            axs[mi] = *(const bf16x8*)(stg[0] + off);
            ass[mi] = *(const bf16x8*)(stg[1] + off);
        }
#pragma unroll
        for (int ni = 0; ni < 4; ++ni) {
            int row = wc * 64 + ni * 16 + fr;
            int off = row * 32 + ((fs ^ ((row >> 1) & 3)) * 8);
            bw[ni]  = *(const bf16x8*)(stg[2] + off);
            bw2[ni] = *(const bf16x8*)(stg[3] + off);
        }
#pragma unroll
        for (int mi = 0; mi < 4; ++mi)
#pragma unroll
            for (int ni = 0; ni < 4; ++ni) {
                a1[mi][ni] = __builtin_amdgcn_mfma_f32_16x16x32_bf16(
                    axs[mi], bw[ni], a1[mi][ni], 0, 0, 0);
                a2[mi][ni] = __builtin_amdgcn_mfma_f32_16x16x32_bf16(
                    ass[mi], bw2[ni], a2[mi][ni], 0, 0, 0);
            }
        __syncthreads();
    }

    // epilogue: out = a1 * rsqrt(a2 + eps) + bias (direct scalar stores; the
    // coalesced-LDS variant saves ~16MB writes but is deferred until this
    // structure's counters are re-baselined)
#pragma unroll
    for (int ni = 0; ni < 4; ++ni) {
        int o = bn * 128 + wc * 64 + ni * 16 + fr;
        float bo = bias[o];
#pragma unroll
        for (int mi = 0; mi < 4; ++mi) {
#pragma unroll
            for (int j = 0; j < 4; ++j) {
                size_t t = (size_t)bm * 128 + wr * 64 + mi * 16 + fs * 4 + j;
                float d = rsqrtf(a2[mi][ni][j] + 1e-8f);
                out[t * DIM + o] = a1[mi][ni][j] * d + bo;
            }
        }
    }
}

extern "C" void kernel_launch(void* const* d_in, const int* in_sizes, int n_in,
                              void* d_out, int out_size, void* d_ws, size_t ws_size,
                              hipStream_t stream) {
    const float* x      = (const float*)d_in[0];
    const float* mod    = (const float*)d_in[1];
    const float* weight = (const float*)d_in[2];
    const float* bias   = (const float*)d_in[3];
    const float* mod_w  = (const float*)d_in[4];
    const float* mod_b  = (const float*)d_in[5];
    float* out = (float*)d_out;

    char* ws = (char*)d_ws;
    unsigned short* modb = (unsigned short*)(ws);
    unsigned short* xs   = (unsigned short*)(ws + (size_t)16777216);
    unsigned short* ssb  = (unsigned short*)(ws + (size_t)2 * 16777216);
    unsigned short* Wb   = (unsigned short*)(ws + (size_t)3 * 16777216);
    unsigned short* W2b  = (unsigned short*)(ws + (size_t)3 * 16777216 + 524288);
    unsigned short* mwb  = (unsigned short*)(ws + (size_t)3 * 16777216 + 2 * 524288);

    hipLaunchKernelGGL(k0_convert, dim3(2048), dim3(256), 0, stream,
                       mod, weight, mod_w, modb, Wb, W2b, mwb);
    hipLaunchKernelGGL(k1_style, dim3(512), dim3(256), 0, stream,
                       modb, mwb, x, mod_b, xs, ssb);
    hipLaunchKernelGGL(k2_main, dim3(512), dim3(256), 0, stream,
                       xs, ssb, Wb, W2b, bias, out);
}

// Round 9
// 72.693 us; speedup vs baseline: 1.8128x; 1.8128x over previous
//
#include <hip/hip_runtime.h>
#include <hip/hip_bf16.h>

// ModulatedLinear: B=4, S=4096, IN=OUT=MOD=512
// out[t,o] = demod[t,o] * sum_i W[o,i]*s[t,i]*x[t,i] + bias[o]
//   s[t,i]    = sum_m mod[t,m]*mod_w[i,m] + mod_b[i]
//   demod[t,o]= rsqrt(sum_i (W[o,i]*s[t,i])^2 + 1e-8)
//
// bf16 MFMA pipeline:
//  K0: fp32->bf16 converts
//  K1: s = modb @ mod_wb^T; LDS-transpose epilogue -> xs, ss (proven)
//  K2: dual GEMM 128x128, BK=64 single-buffered (R4 core: 0 conflicts,
//      38us) + XCD swizzle + NEW LDS-transpose epilogue (float4 stores).
//      NOTE: DMA-dbuf is a dead end here — R5-R7 showed concurrent
//      global_load_lds writes || ds_reads cost 1.34e7 bank conflicts
//      regardless of static patterns (R7 changed readback, counter frozen;
//      R8 single-buffered, counter 0). launch_bounds must stay (256,2):
//      (256,4) forced VGPR=64 -> acc spills -> 291MB scratch writes (R8).

#define T_TOK 16384
#define DIM 512

typedef __attribute__((ext_vector_type(4))) float f32x4;
typedef __attribute__((ext_vector_type(8))) short bf16x8;

static __device__ __forceinline__ unsigned short f2bf(float f) {
    union { float f; unsigned int u; } v; v.f = f;
    unsigned int u = v.u;
    u += 0x7fffu + ((u >> 16) & 1u);   // RNE
    return (unsigned short)(u >> 16);
}
static __device__ __forceinline__ float bf2f(unsigned short h) {
    union { unsigned int u; float f; } v; v.u = ((unsigned int)h) << 16;
    return v.f;
}

// ---------------- K0: converts ----------------
__global__ __launch_bounds__(256) void k0_convert(
    const float* __restrict__ mod, const float* __restrict__ weight,
    const float* __restrict__ mod_w,
    unsigned short* __restrict__ modb, unsigned short* __restrict__ Wb,
    unsigned short* __restrict__ W2b, unsigned short* __restrict__ mwb)
{
    const int NV_MOD = (T_TOK * DIM) / 4;
    const int NV_W   = (DIM * DIM) / 4;
    int idx = blockIdx.x * blockDim.x + threadIdx.x;
    int stride = gridDim.x * blockDim.x;
    for (int i = idx; i < NV_MOD; i += stride) {
        f32x4 v = ((const f32x4*)mod)[i];
        ushort4 o; o.x = f2bf(v[0]); o.y = f2bf(v[1]); o.z = f2bf(v[2]); o.w = f2bf(v[3]);
        ((ushort4*)modb)[i] = o;
    }
    for (int i = idx; i < NV_W; i += stride) {
        f32x4 v = ((const f32x4*)weight)[i];
        ushort4 o;  o.x = f2bf(v[0]); o.y = f2bf(v[1]); o.z = f2bf(v[2]); o.w = f2bf(v[3]);
        ((ushort4*)Wb)[i] = o;
        ushort4 o2; o2.x = f2bf(v[0]*v[0]); o2.y = f2bf(v[1]*v[1]);
                    o2.z = f2bf(v[2]*v[2]); o2.w = f2bf(v[3]*v[3]);
        ((ushort4*)W2b)[i] = o2;
        f32x4 m = ((const f32x4*)mod_w)[i];
        ushort4 o3; o3.x = f2bf(m[0]); o3.y = f2bf(m[1]); o3.z = f2bf(m[2]); o3.w = f2bf(m[3]);
        ((ushort4*)mwb)[i] = o3;
    }
}

// LDS tiles: [rows][64] bf16, physical 16B-slot = logical ^ (row & 7).
// global_load_lds writes wave-uniform-base + lane*16, so the GLOBAL source
// address carries the swizzle (both-sides-or-neither).

// ---------------- K1: s-GEMM + LDS-transpose epilogue (unchanged) ----------------
__global__ __launch_bounds__(256, 2) void k1_style(
    const unsigned short* __restrict__ modb,   // [T][512] bf16
    const unsigned short* __restrict__ mwb,    // [512][512] bf16 (IN x MOD)
    const float* __restrict__ x,               // [T][512] fp32
    const float* __restrict__ mod_b,           // [512]
    unsigned short* __restrict__ xs,           // [T][512] bf16 out
    unsigned short* __restrict__ ss)           // [T][512] bf16 out
{
    __shared__ union {
        struct { unsigned short A[128 * 64]; unsigned short B[128 * 64]; } stg;
        unsigned short str[128 * 144];
    } u;
    const int tid  = threadIdx.x;
    const int lane = tid & 63;
    const int w    = tid >> 6;
    const int wr   = w >> 1, wc = w & 1;
    const int nbn  = DIM / 128;
    const int bm   = blockIdx.x / nbn;
    const int bn   = blockIdx.x % nbn;

    const int srow  = lane >> 3;
    const int lslot = (lane & 7) ^ srow;
    const int fr    = lane & 15;
    const int fs    = lane >> 4;

    f32x4 acc[4][4] = {};

    const size_t aBase = (size_t)bm * 128 * DIM;
    const size_t bBase = (size_t)bn * 128 * DIM;

    for (int kb = 0; kb < DIM; kb += 64) {
#pragma unroll
        for (int q = 0; q < 4; ++q) {
            int row = w * 32 + q * 8 + srow;
            const unsigned short* ga = modb + aBase + (size_t)row * DIM + kb + lslot * 8;
            const unsigned short* gb = mwb  + bBase + (size_t)row * DIM + kb + lslot * 8;
            __builtin_amdgcn_global_load_lds(
                (__attribute__((address_space(1))) void*)ga,
                (__attribute__((address_space(3))) void*)(u.stg.A + w * 2048 + q * 512), 16, 0, 0);
            __builtin_amdgcn_global_load_lds(
                (__attribute__((address_space(1))) void*)gb,
                (__attribute__((address_space(3))) void*)(u.stg.B + w * 2048 + q * 512), 16, 0, 0);
        }
        __syncthreads();
#pragma unroll
        for (int kk = 0; kk < 64; kk += 32) {
            bf16x8 af[4], bfv[4];
#pragma unroll
            for (int mi = 0; mi < 4; ++mi) {
                int row = wr * 64 + mi * 16 + fr;
                int ps  = ((kk >> 3) + fs) ^ (fr & 7);
                af[mi] = *(const bf16x8*)(u.stg.A + row * 64 + ps * 8);
            }
#pragma unroll
            for (int ni = 0; ni < 4; ++ni) {
                int row = wc * 64 + ni * 16 + fr;
                int ps  = ((kk >> 3) + fs) ^ (fr & 7);
                bfv[ni] = *(const bf16x8*)(u.stg.B + row * 64 + ps * 8);
            }
#pragma unroll
            for (int mi = 0; mi < 4; ++mi)
#pragma unroll
                for (int ni = 0; ni < 4; ++ni)
                    acc[mi][ni] = __builtin_amdgcn_mfma_f32_16x16x32_bf16(
                        af[mi], bfv[ni], acc[mi][ni], 0, 0, 0);
        }
        __syncthreads();
    }

#pragma unroll
    for (int ni = 0; ni < 4; ++ni) {
        int col = wc * 64 + ni * 16 + fr;
        float mb = mod_b[bn * 128 + col];
#pragma unroll
        for (int mi = 0; mi < 4; ++mi) {
#pragma unroll
            for (int j = 0; j < 4; ++j) {
                int row = wr * 64 + mi * 16 + fs * 4 + j;
                u.str[row * 144 + col] = f2bf(acc[mi][ni][j] + mb);
            }
        }
    }
    __syncthreads();
#pragma unroll
    for (int q = 0; q < 8; ++q) {
        int row = w * 32 + q * 4 + (lane >> 4);
        int c8  = (lane & 15) * 8;
        bf16x8 s8 = *(const bf16x8*)(u.str + row * 144 + c8);
        size_t off = ((size_t)bm * 128 + row) * DIM + bn * 128 + c8;
        f32x4 x0 = *(const f32x4*)(x + off);
        f32x4 x1 = *(const f32x4*)(x + off + 4);
        bf16x8 xsv, ssv;
#pragma unroll
        for (int e = 0; e < 8; ++e) {
            float sf = bf2f((unsigned short)s8[e]);
            float xv = (e < 4) ? x0[e] : x1[e - 4];
            xsv[e] = (short)f2bf(xv * sf);
            ssv[e] = (short)f2bf(sf * sf);
        }
        *(bf16x8*)(xs + off) = xsv;
        *(bf16x8*)(ss + off) = ssv;
    }
}

// ---------------- K2: dual GEMM 128x128 (R4 core) + LDS-transpose epilogue ----
__global__ __launch_bounds__(256, 2) void k2_main(
    const unsigned short* __restrict__ xs,   // [T][512] bf16
    const unsigned short* __restrict__ ss,   // [T][512] bf16
    const unsigned short* __restrict__ Wb,   // [512][512] bf16 (OUT x IN)
    const unsigned short* __restrict__ W2b,  // [512][512] bf16
    const float* __restrict__ bias,          // [512]
    float* __restrict__ out)                 // [T][512] fp32
{
    __shared__ union {
        struct {
            unsigned short XS[128 * 64];
            unsigned short SS[128 * 64];
            unsigned short W [128 * 64];
            unsigned short W2[128 * 64];
        } stg;                               // 64KB
        float tr[128 * 132];                 // 67.6KB out-transpose buffer
    } u;
    const int tid  = threadIdx.x;
    const int lane = tid & 63;
    const int w    = tid >> 6;
    const int wr   = w >> 1, wc = w & 1;
    // XCD-chunked bijective swizzle (512 blocks, 64/XCD)
    const int tile = (blockIdx.x & 7) * 64 + (blockIdx.x >> 3);
    const int bm   = tile >> 2;
    const int bn   = tile & 3;

    const int srow  = lane >> 3;
    const int lslot = (lane & 7) ^ srow;
    const int fr    = lane & 15;
    const int fs    = lane >> 4;

    f32x4 a1[4][4] = {};
    f32x4 a2[4][4] = {};

    const size_t aBase = (size_t)bm * 128 * DIM;
    const size_t bBase = (size_t)bn * 128 * DIM;

    for (int kb = 0; kb < DIM; kb += 64) {
#pragma unroll
        for (int q = 0; q < 4; ++q) {
            int row = w * 32 + q * 8 + srow;
            size_t goffA = aBase + (size_t)row * DIM + kb + lslot * 8;
            size_t goffB = bBase + (size_t)row * DIM + kb + lslot * 8;
            unsigned ldso = w * 2048 + q * 512;
            __builtin_amdgcn_global_load_lds(
                (__attribute__((address_space(1))) void*)(xs + goffA),
                (__attribute__((address_space(3))) void*)(u.stg.XS + ldso), 16, 0, 0);
            __builtin_amdgcn_global_load_lds(
                (__attribute__((address_space(1))) void*)(ss + goffA),
                (__attribute__((address_space(3))) void*)(u.stg.SS + ldso), 16, 0, 0);
            __builtin_amdgcn_global_load_lds(
                (__attribute__((address_space(1))) void*)(Wb + goffB),
                (__attribute__((address_space(3))) void*)(u.stg.W + ldso), 16, 0, 0);
            __builtin_amdgcn_global_load_lds(
                (__attribute__((address_space(1))) void*)(W2b + goffB),
                (__attribute__((address_space(3))) void*)(u.stg.W2 + ldso), 16, 0, 0);
        }
        __syncthreads();
#pragma unroll
        for (int kk = 0; kk < 64; kk += 32) {
            bf16x8 axs[4], ass[4], bw[4], bw2[4];
#pragma unroll
            for (int mi = 0; mi < 4; ++mi) {
                int row = wr * 64 + mi * 16 + fr;
                int ps  = ((kk >> 3) + fs) ^ (fr & 7);
                axs[mi] = *(const bf16x8*)(u.stg.XS + row * 64 + ps * 8);
                ass[mi] = *(const bf16x8*)(u.stg.SS + row * 64 + ps * 8);
            }
#pragma unroll
            for (int ni = 0; ni < 4; ++ni) {
                int row = wc * 64 + ni * 16 + fr;
                int ps  = ((kk >> 3) + fs) ^ (fr & 7);
                bw[ni]  = *(const bf16x8*)(u.stg.W  + row * 64 + ps * 8);
                bw2[ni] = *(const bf16x8*)(u.stg.W2 + row * 64 + ps * 8);
            }
#pragma unroll
            for (int mi = 0; mi < 4; ++mi)
#pragma unroll
                for (int ni = 0; ni < 4; ++ni) {
                    a1[mi][ni] = __builtin_amdgcn_mfma_f32_16x16x32_bf16(
                        axs[mi], bw[ni], a1[mi][ni], 0, 0, 0);
                    a2[mi][ni] = __builtin_amdgcn_mfma_f32_16x16x32_bf16(
                        ass[mi], bw2[ni], a2[mi][ni], 0, 0, 0);
                }
        }
        __syncthreads();
    }

    // epilogue: demod+bias -> LDS fp32 [128][132] -> float4 coalesced stores.
    // scatter bank = (16fs + 4j + 16ni + fr) mod 32 -> 2 lanes/bank (free).
#pragma unroll
    for (int ni = 0; ni < 4; ++ni) {
        int col = wc * 64 + ni * 16 + fr;
        float bo = bias[bn * 128 + col];
#pragma unroll
        for (int mi = 0; mi < 4; ++mi) {
#pragma unroll
            for (int j = 0; j < 4; ++j) {
                int row = wr * 64 + mi * 16 + fs * 4 + j;
                float d = rsqrtf(a2[mi][ni][j] + 1e-8f);
                u.tr[row * 132 + col] = a1[mi][ni][j] * d + bo;
            }
        }
    }
    __syncthreads();
    // readback: 16 lanes/row (g=lane>>4: row += g>>1, half = g&1).
    // quad = (4row + 4fr) span -> 2 lanes/quad (free). Each 16-lane group
    // stores 256B contiguous; two groups complete each 512B output line.
#pragma unroll
    for (int i = 0; i < 16; ++i) {
        int g   = lane >> 4;                       // 0..3
        int row = w * 32 + i * 2 + (g >> 1);
        int col = (g & 1) * 64 + (lane & 15) * 4;
        f32x4 v = *(const f32x4*)(u.tr + row * 132 + col);
        *(f32x4*)(out + ((size_t)bm * 128 + row) * DIM + bn * 128 + col) = v;
    }
}

extern "C" void kernel_launch(void* const* d_in, const int* in_sizes, int n_in,
                              void* d_out, int out_size, void* d_ws, size_t ws_size,
                              hipStream_t stream) {
    const float* x      = (const float*)d_in[0];
    const float* mod    = (const float*)d_in[1];
    const float* weight = (const float*)d_in[2];
    const float* bias   = (const float*)d_in[3];
    const float* mod_w  = (const float*)d_in[4];
    const float* mod_b  = (const float*)d_in[5];
    float* out = (float*)d_out;

    char* ws = (char*)d_ws;
    unsigned short* modb = (unsigned short*)(ws);
    unsigned short* xs   = (unsigned short*)(ws + (size_t)16777216);
    unsigned short* ssb  = (unsigned short*)(ws + (size_t)2 * 16777216);
    unsigned short* Wb   = (unsigned short*)(ws + (size_t)3 * 16777216);
    unsigned short* W2b  = (unsigned short*)(ws + (size_t)3 * 16777216 + 524288);
    unsigned short* mwb  = (unsigned short*)(ws + (size_t)3 * 16777216 + 2 * 524288);

    hipLaunchKernelGGL(k0_convert, dim3(2048), dim3(256), 0, stream,
                       mod, weight, mod_w, modb, Wb, W2b, mwb);
    hipLaunchKernelGGL(k1_style, dim3(512), dim3(256), 0, stream,
                       modb, mwb, x, mod_b, xs, ssb);
    hipLaunchKernelGGL(k2_main, dim3(512), dim3(256), 0, stream,
                       xs, ssb, Wb, W2b, bias, out);
}

// Round 10
// 60.839 us; speedup vs baseline: 2.1660x; 1.1948x over previous
//
#include <hip/hip_runtime.h>
#include <hip/hip_bf16.h>

// ModulatedLinear: B=4, S=4096, IN=OUT=MOD=512
// out[t,o] = demod[t,o] * sum_i W[o,i]*s[t,i]*x[t,i] + bias[o]
//   s[t,i]    = sum_m mod[t,m]*mod_w[i,m] + mod_b[i]
//   demod[t,o]= rsqrt(sum_i (W[o,i]*s[t,i])^2 + 1e-8)
//
// bf16 MFMA pipeline:
//  K0: fp32->bf16 converts
//  K1: s = modb @ mod_wb^T; bf16 LDS-transpose epilogue -> xs, ss (0-conflict)
//  K2: dual GEMM 128x128, BK=32 single-buffered, __launch_bounds__(256,3)
//      -> 3 blocks/CU (VGPR cap ~170: no spill, unlike R8's (256,4) cap 64
//      which spilled 291MB). Direct-store epilogue.
//      EMPIRICAL BAN: fp32 LDS-transpose epilogue costs 1.337e7 bank-conflict
//      cycles (~15us) regardless of scatter/readback/buffering variant
//      (R5,R6,R7,R9); direct stores measure 0 (R2,R4,R8). Mechanism unknown;
//      static bank arithmetic says clean — trust the counter, not the model.

#define T_TOK 16384
#define DIM 512

typedef __attribute__((ext_vector_type(4))) float f32x4;
typedef __attribute__((ext_vector_type(8))) short bf16x8;

static __device__ __forceinline__ unsigned short f2bf(float f) {
    union { float f; unsigned int u; } v; v.f = f;
    unsigned int u = v.u;
    u += 0x7fffu + ((u >> 16) & 1u);   // RNE
    return (unsigned short)(u >> 16);
}
static __device__ __forceinline__ float bf2f(unsigned short h) {
    union { unsigned int u; float f; } v; v.u = ((unsigned int)h) << 16;
    return v.f;
}

// ---------------- K0: converts ----------------
__global__ __launch_bounds__(256) void k0_convert(
    const float* __restrict__ mod, const float* __restrict__ weight,
    const float* __restrict__ mod_w,
    unsigned short* __restrict__ modb, unsigned short* __restrict__ Wb,
    unsigned short* __restrict__ W2b, unsigned short* __restrict__ mwb)
{
    const int NV_MOD = (T_TOK * DIM) / 4;
    const int NV_W   = (DIM * DIM) / 4;
    int idx = blockIdx.x * blockDim.x + threadIdx.x;
    int stride = gridDim.x * blockDim.x;
    for (int i = idx; i < NV_MOD; i += stride) {
        f32x4 v = ((const f32x4*)mod)[i];
        ushort4 o; o.x = f2bf(v[0]); o.y = f2bf(v[1]); o.z = f2bf(v[2]); o.w = f2bf(v[3]);
        ((ushort4*)modb)[i] = o;
    }
    for (int i = idx; i < NV_W; i += stride) {
        f32x4 v = ((const f32x4*)weight)[i];
        ushort4 o;  o.x = f2bf(v[0]); o.y = f2bf(v[1]); o.z = f2bf(v[2]); o.w = f2bf(v[3]);
        ((ushort4*)Wb)[i] = o;
        ushort4 o2; o2.x = f2bf(v[0]*v[0]); o2.y = f2bf(v[1]*v[1]);
                    o2.z = f2bf(v[2]*v[2]); o2.w = f2bf(v[3]*v[3]);
        ((ushort4*)W2b)[i] = o2;
        f32x4 m = ((const f32x4*)mod_w)[i];
        ushort4 o3; o3.x = f2bf(m[0]); o3.y = f2bf(m[1]); o3.z = f2bf(m[2]); o3.w = f2bf(m[3]);
        ((ushort4*)mwb)[i] = o3;
    }
}

// ---------------- K1: s-GEMM + bf16 LDS-transpose epilogue (unchanged) ------
__global__ __launch_bounds__(256, 2) void k1_style(
    const unsigned short* __restrict__ modb,   // [T][512] bf16
    const unsigned short* __restrict__ mwb,    // [512][512] bf16 (IN x MOD)
    const float* __restrict__ x,               // [T][512] fp32
    const float* __restrict__ mod_b,           // [512]
    unsigned short* __restrict__ xs,           // [T][512] bf16 out
    unsigned short* __restrict__ ss)           // [T][512] bf16 out
{
    __shared__ union {
        struct { unsigned short A[128 * 64]; unsigned short B[128 * 64]; } stg;
        unsigned short str[128 * 144];
    } u;
    const int tid  = threadIdx.x;
    const int lane = tid & 63;
    const int w    = tid >> 6;
    const int wr   = w >> 1, wc = w & 1;
    const int nbn  = DIM / 128;
    const int bm   = blockIdx.x / nbn;
    const int bn   = blockIdx.x % nbn;

    const int srow  = lane >> 3;
    const int lslot = (lane & 7) ^ srow;
    const int fr    = lane & 15;
    const int fs    = lane >> 4;

    f32x4 acc[4][4] = {};

    const size_t aBase = (size_t)bm * 128 * DIM;
    const size_t bBase = (size_t)bn * 128 * DIM;

    for (int kb = 0; kb < DIM; kb += 64) {
#pragma unroll
        for (int q = 0; q < 4; ++q) {
            int row = w * 32 + q * 8 + srow;
            const unsigned short* ga = modb + aBase + (size_t)row * DIM + kb + lslot * 8;
            const unsigned short* gb = mwb  + bBase + (size_t)row * DIM + kb + lslot * 8;
            __builtin_amdgcn_global_load_lds(
                (__attribute__((address_space(1))) void*)ga,
                (__attribute__((address_space(3))) void*)(u.stg.A + w * 2048 + q * 512), 16, 0, 0);
            __builtin_amdgcn_global_load_lds(
                (__attribute__((address_space(1))) void*)gb,
                (__attribute__((address_space(3))) void*)(u.stg.B + w * 2048 + q * 512), 16, 0, 0);
        }
        __syncthreads();
#pragma unroll
        for (int kk = 0; kk < 64; kk += 32) {
            bf16x8 af[4], bfv[4];
#pragma unroll
            for (int mi = 0; mi < 4; ++mi) {
                int row = wr * 64 + mi * 16 + fr;
                int ps  = ((kk >> 3) + fs) ^ (fr & 7);
                af[mi] = *(const bf16x8*)(u.stg.A + row * 64 + ps * 8);
            }
#pragma unroll
            for (int ni = 0; ni < 4; ++ni) {
                int row = wc * 64 + ni * 16 + fr;
                int ps  = ((kk >> 3) + fs) ^ (fr & 7);
                bfv[ni] = *(const bf16x8*)(u.stg.B + row * 64 + ps * 8);
            }
#pragma unroll
            for (int mi = 0; mi < 4; ++mi)
#pragma unroll
                for (int ni = 0; ni < 4; ++ni)
                    acc[mi][ni] = __builtin_amdgcn_mfma_f32_16x16x32_bf16(
                        af[mi], bfv[ni], acc[mi][ni], 0, 0, 0);
        }
        __syncthreads();
    }

#pragma unroll
    for (int ni = 0; ni < 4; ++ni) {
        int col = wc * 64 + ni * 16 + fr;
        float mb = mod_b[bn * 128 + col];
#pragma unroll
        for (int mi = 0; mi < 4; ++mi) {
#pragma unroll
            for (int j = 0; j < 4; ++j) {
                int row = wr * 64 + mi * 16 + fs * 4 + j;
                u.str[row * 144 + col] = f2bf(acc[mi][ni][j] + mb);
            }
        }
    }
    __syncthreads();
#pragma unroll
    for (int q = 0; q < 8; ++q) {
        int row = w * 32 + q * 4 + (lane >> 4);
        int c8  = (lane & 15) * 8;
        bf16x8 s8 = *(const bf16x8*)(u.str + row * 144 + c8);
        size_t off = ((size_t)bm * 128 + row) * DIM + bn * 128 + c8;
        f32x4 x0 = *(const f32x4*)(x + off);
        f32x4 x1 = *(const f32x4*)(x + off + 4);
        bf16x8 xsv, ssv;
#pragma unroll
        for (int e = 0; e < 8; ++e) {
            float sf = bf2f((unsigned short)s8[e]);
            float xv = (e < 4) ? x0[e] : x1[e - 4];
            xsv[e] = (short)f2bf(xv * sf);
            ssv[e] = (short)f2bf(sf * sf);
        }
        *(bf16x8*)(xs + off) = xsv;
        *(bf16x8*)(ss + off) = ssv;
    }
}

// ---------------- K2: dual GEMM 128x128, BK=32 single-buf, 3 blk/CU ---------
// LDS [128 rows][32 cols] bf16 = 8KB/stream (32KB total); phys 16B-slot =
// logical ^ ((row>>1)&3) (verified 0-conflict in R8). STAGE/COMPUTE are
// barrier-separated. Direct-store epilogue (0-conflict family).
__global__ __launch_bounds__(256, 3) void k2_main(
    const unsigned short* __restrict__ xs,   // [T][512] bf16
    const unsigned short* __restrict__ ss,   // [T][512] bf16
    const unsigned short* __restrict__ Wb,   // [512][512] bf16 (OUT x IN)
    const unsigned short* __restrict__ W2b,  // [512][512] bf16
    const float* __restrict__ bias,          // [512]
    float* __restrict__ out)                 // [T][512] fp32
{
    __shared__ unsigned short stg[4][128 * 32];   // 32KB total
    const int tid  = threadIdx.x;
    const int lane = tid & 63;
    const int w    = tid >> 6;
    const int wr   = w >> 1, wc = w & 1;
    // XCD-chunked bijective swizzle (512 blocks, 64/XCD)
    const int tile = (blockIdx.x & 7) * 64 + (blockIdx.x >> 3);
    const int bm   = tile >> 2;
    const int bn   = tile & 3;

    const int fr = lane & 15;
    const int fs = lane >> 4;

    f32x4 a1[4][4] = {};
    f32x4 a2[4][4] = {};

    const size_t aBase = (size_t)bm * 128 * DIM;
    const size_t bBase = (size_t)bn * 128 * DIM;

    // staging: one wave-issue = 1KB = 16 rows x 4 slots
    const int srw = lane >> 2;             // row within issue
    const int sp  = lane & 3;              // phys slot written by this lane

    for (int kb = 0; kb < DIM; kb += 32) {
#pragma unroll
        for (int q = 0; q < 2; ++q) {
            int rb   = w * 32 + q * 16;
            int row  = rb + srw;
            int slog = sp ^ ((row >> 1) & 3);   // involutive swizzle
            size_t gA = aBase + (size_t)row * DIM + kb + slog * 8;
            size_t gB = bBase + (size_t)row * DIM + kb + slog * 8;
            __builtin_amdgcn_global_load_lds(
                (__attribute__((address_space(1))) void*)(xs + gA),
                (__attribute__((address_space(3))) void*)(stg[0] + rb * 32), 16, 0, 0);
            __builtin_amdgcn_global_load_lds(
                (__attribute__((address_space(1))) void*)(ss + gA),
                (__attribute__((address_space(3))) void*)(stg[1] + rb * 32), 16, 0, 0);
            __builtin_amdgcn_global_load_lds(
                (__attribute__((address_space(1))) void*)(Wb + gB),
                (__attribute__((address_space(3))) void*)(stg[2] + rb * 32), 16, 0, 0);
            __builtin_amdgcn_global_load_lds(
                (__attribute__((address_space(1))) void*)(W2b + gB),
                (__attribute__((address_space(3))) void*)(stg[3] + rb * 32), 16, 0, 0);
        }
        __syncthreads();

        bf16x8 axs[4], ass[4], bw[4], bw2[4];
#pragma unroll
        for (int mi = 0; mi < 4; ++mi) {
            int row = wr * 64 + mi * 16 + fr;
            int off = row * 32 + ((fs ^ ((row >> 1) & 3)) * 8);
            axs[mi] = *(const bf16x8*)(stg[0] + off);
            ass[mi] = *(const bf16x8*)(stg[1] + off);
        }
#pragma unroll
        for (int ni = 0; ni < 4; ++ni) {
            int row = wc * 64 + ni * 16 + fr;
            int off = row * 32 + ((fs ^ ((row >> 1) & 3)) * 8);
            bw[ni]  = *(const bf16x8*)(stg[2] + off);
            bw2[ni] = *(const bf16x8*)(stg[3] + off);
        }
#pragma unroll
        for (int mi = 0; mi < 4; ++mi)
#pragma unroll
            for (int ni = 0; ni < 4; ++ni) {
                a1[mi][ni] = __builtin_amdgcn_mfma_f32_16x16x32_bf16(
                    axs[mi], bw[ni], a1[mi][ni], 0, 0, 0);
                a2[mi][ni] = __builtin_amdgcn_mfma_f32_16x16x32_bf16(
                    ass[mi], bw2[ni], a2[mi][ni], 0, 0, 0);
            }
        __syncthreads();
    }

    // epilogue: out = a1 * rsqrt(a2 + eps) + bias (direct stores, 0-conflict)
#pragma unroll
    for (int ni = 0; ni < 4; ++ni) {
        int o = bn * 128 + wc * 64 + ni * 16 + fr;
        float bo = bias[o];
#pragma unroll
        for (int mi = 0; mi < 4; ++mi) {
#pragma unroll
            for (int j = 0; j < 4; ++j) {
                size_t t = (size_t)bm * 128 + wr * 64 + mi * 16 + fs * 4 + j;
                float d = rsqrtf(a2[mi][ni][j] + 1e-8f);
                out[t * DIM + o] = a1[mi][ni][j] * d + bo;
            }
        }
    }
}

extern "C" void kernel_launch(void* const* d_in, const int* in_sizes, int n_in,
                              void* d_out, int out_size, void* d_ws, size_t ws_size,
                              hipStream_t stream) {
    const float* x      = (const float*)d_in[0];
    const float* mod    = (const float*)d_in[1];
    const float* weight = (const float*)d_in[2];
    const float* bias   = (const float*)d_in[3];
    const float* mod_w  = (const float*)d_in[4];
    const float* mod_b  = (const float*)d_in[5];
    float* out = (float*)d_out;

    char* ws = (char*)d_ws;
    unsigned short* modb = (unsigned short*)(ws);
    unsigned short* xs   = (unsigned short*)(ws + (size_t)16777216);
    unsigned short* ssb  = (unsigned short*)(ws + (size_t)2 * 16777216);
    unsigned short* Wb   = (unsigned short*)(ws + (size_t)3 * 16777216);
    unsigned short* W2b  = (unsigned short*)(ws + (size_t)3 * 16777216 + 524288);
    unsigned short* mwb  = (unsigned short*)(ws + (size_t)3 * 16777216 + 2 * 524288);

    hipLaunchKernelGGL(k0_convert, dim3(2048), dim3(256), 0, stream,
                       mod, weight, mod_w, modb, Wb, W2b, mwb);
    hipLaunchKernelGGL(k1_style, dim3(512), dim3(256), 0, stream,
                       modb, mwb, x, mod_b, xs, ssb);
    hipLaunchKernelGGL(k2_main, dim3(512), dim3(256), 0, stream,
                       xs, ssb, Wb, W2b, bias, out);
}

// Round 11
// 58.976 us; speedup vs baseline: 2.2345x; 1.0316x over previous
//
#include <hip/hip_runtime.h>
#include <hip/hip_bf16.h>

// ModulatedLinear: B=4, S=4096, IN=OUT=MOD=512
// out[t,o] = demod[t,o] * sum_i W[o,i]*s[t,i]*x[t,i] + bias[o]
//   s[t,i]    = sum_m mod[t,m]*mod_w[i,m] + mod_b[i]
//   demod[t,o]= rsqrt(sum_i (W[o,i]*s[t,i])^2 + 1e-8)
//
// bf16 MFMA pipeline:
//  K0: fp32->bf16 converts
//  K1: s = modb @ mod_wb^T; bf16 LDS-transpose epilogue -> xs, ss (0-conflict)
//  K2: dual GEMM 128x128, BK=32, 2-deep COUNTED-VMCNT pipeline (T4):
//      raw s_barrier + vmcnt(8) so prefetch stays in flight across barriers.
//      All prior "dbuf" attempts used __syncthreads (vmcnt(0) drain of the
//      just-issued prefetch) = guide's drain0 null case (m218). This is the
//      first true counted pipeline.
//      Bans (empirical): fp32 LDS-tr epilogue (+1.34e7 conflict cycles,
//      R5/R6/R7/R9); launch_bounds(256,4) (VGPR=64 -> 291MB spills, R8).

#define T_TOK 16384
#define DIM 512

typedef __attribute__((ext_vector_type(4))) float f32x4;
typedef __attribute__((ext_vector_type(8))) short bf16x8;

static __device__ __forceinline__ unsigned short f2bf(float f) {
    union { float f; unsigned int u; } v; v.f = f;
    unsigned int u = v.u;
    u += 0x7fffu + ((u >> 16) & 1u);   // RNE
    return (unsigned short)(u >> 16);
}
static __device__ __forceinline__ float bf2f(unsigned short h) {
    union { unsigned int u; float f; } v; v.u = ((unsigned int)h) << 16;
    return v.f;
}

// ---------------- K0: converts ----------------
__global__ __launch_bounds__(256) void k0_convert(
    const float* __restrict__ mod, const float* __restrict__ weight,
    const float* __restrict__ mod_w,
    unsigned short* __restrict__ modb, unsigned short* __restrict__ Wb,
    unsigned short* __restrict__ W2b, unsigned short* __restrict__ mwb)
{
    const int NV_MOD = (T_TOK * DIM) / 4;
    const int NV_W   = (DIM * DIM) / 4;
    int idx = blockIdx.x * blockDim.x + threadIdx.x;
    int stride = gridDim.x * blockDim.x;
    for (int i = idx; i < NV_MOD; i += stride) {
        f32x4 v = ((const f32x4*)mod)[i];
        ushort4 o; o.x = f2bf(v[0]); o.y = f2bf(v[1]); o.z = f2bf(v[2]); o.w = f2bf(v[3]);
        ((ushort4*)modb)[i] = o;
    }
    for (int i = idx; i < NV_W; i += stride) {
        f32x4 v = ((const f32x4*)weight)[i];
        ushort4 o;  o.x = f2bf(v[0]); o.y = f2bf(v[1]); o.z = f2bf(v[2]); o.w = f2bf(v[3]);
        ((ushort4*)Wb)[i] = o;
        ushort4 o2; o2.x = f2bf(v[0]*v[0]); o2.y = f2bf(v[1]*v[1]);
                    o2.z = f2bf(v[2]*v[2]); o2.w = f2bf(v[3]*v[3]);
        ((ushort4*)W2b)[i] = o2;
        f32x4 m = ((const f32x4*)mod_w)[i];
        ushort4 o3; o3.x = f2bf(m[0]); o3.y = f2bf(m[1]); o3.z = f2bf(m[2]); o3.w = f2bf(m[3]);
        ((ushort4*)mwb)[i] = o3;
    }
}

// ---------------- K1: s-GEMM + bf16 LDS-transpose epilogue (unchanged) ------
__global__ __launch_bounds__(256, 2) void k1_style(
    const unsigned short* __restrict__ modb,   // [T][512] bf16
    const unsigned short* __restrict__ mwb,    // [512][512] bf16 (IN x MOD)
    const float* __restrict__ x,               // [T][512] fp32
    const float* __restrict__ mod_b,           // [512]
    unsigned short* __restrict__ xs,           // [T][512] bf16 out
    unsigned short* __restrict__ ss)           // [T][512] bf16 out
{
    __shared__ union {
        struct { unsigned short A[128 * 64]; unsigned short B[128 * 64]; } stg;
        unsigned short str[128 * 144];
    } u;
    const int tid  = threadIdx.x;
    const int lane = tid & 63;
    const int w    = tid >> 6;
    const int wr   = w >> 1, wc = w & 1;
    const int nbn  = DIM / 128;
    const int bm   = blockIdx.x / nbn;
    const int bn   = blockIdx.x % nbn;

    const int srow  = lane >> 3;
    const int lslot = (lane & 7) ^ srow;
    const int fr    = lane & 15;
    const int fs    = lane >> 4;

    f32x4 acc[4][4] = {};

    const size_t aBase = (size_t)bm * 128 * DIM;
    const size_t bBase = (size_t)bn * 128 * DIM;

    for (int kb = 0; kb < DIM; kb += 64) {
#pragma unroll
        for (int q = 0; q < 4; ++q) {
            int row = w * 32 + q * 8 + srow;
            const unsigned short* ga = modb + aBase + (size_t)row * DIM + kb + lslot * 8;
            const unsigned short* gb = mwb  + bBase + (size_t)row * DIM + kb + lslot * 8;
            __builtin_amdgcn_global_load_lds(
                (__attribute__((address_space(1))) void*)ga,
                (__attribute__((address_space(3))) void*)(u.stg.A + w * 2048 + q * 512), 16, 0, 0);
            __builtin_amdgcn_global_load_lds(
                (__attribute__((address_space(1))) void*)gb,
                (__attribute__((address_space(3))) void*)(u.stg.B + w * 2048 + q * 512), 16, 0, 0);
        }
        __syncthreads();
#pragma unroll
        for (int kk = 0; kk < 64; kk += 32) {
            bf16x8 af[4], bfv[4];
#pragma unroll
            for (int mi = 0; mi < 4; ++mi) {
                int row = wr * 64 + mi * 16 + fr;
                int ps  = ((kk >> 3) + fs) ^ (fr & 7);
                af[mi] = *(const bf16x8*)(u.stg.A + row * 64 + ps * 8);
            }
#pragma unroll
            for (int ni = 0; ni < 4; ++ni) {
                int row = wc * 64 + ni * 16 + fr;
                int ps  = ((kk >> 3) + fs) ^ (fr & 7);
                bfv[ni] = *(const bf16x8*)(u.stg.B + row * 64 + ps * 8);
            }
#pragma unroll
            for (int mi = 0; mi < 4; ++mi)
#pragma unroll
                for (int ni = 0; ni < 4; ++ni)
                    acc[mi][ni] = __builtin_amdgcn_mfma_f32_16x16x32_bf16(
                        af[mi], bfv[ni], acc[mi][ni], 0, 0, 0);
        }
        __syncthreads();
    }

#pragma unroll
    for (int ni = 0; ni < 4; ++ni) {
        int col = wc * 64 + ni * 16 + fr;
        float mb = mod_b[bn * 128 + col];
#pragma unroll
        for (int mi = 0; mi < 4; ++mi) {
#pragma unroll
            for (int j = 0; j < 4; ++j) {
                int row = wr * 64 + mi * 16 + fs * 4 + j;
                u.str[row * 144 + col] = f2bf(acc[mi][ni][j] + mb);
            }
        }
    }
    __syncthreads();
#pragma unroll
    for (int q = 0; q < 8; ++q) {
        int row = w * 32 + q * 4 + (lane >> 4);
        int c8  = (lane & 15) * 8;
        bf16x8 s8 = *(const bf16x8*)(u.str + row * 144 + c8);
        size_t off = ((size_t)bm * 128 + row) * DIM + bn * 128 + c8;
        f32x4 x0 = *(const f32x4*)(x + off);
        f32x4 x1 = *(const f32x4*)(x + off + 4);
        bf16x8 xsv, ssv;
#pragma unroll
        for (int e = 0; e < 8; ++e) {
            float sf = bf2f((unsigned short)s8[e]);
            float xv = (e < 4) ? x0[e] : x1[e - 4];
            xsv[e] = (short)f2bf(xv * sf);
            ssv[e] = (short)f2bf(sf * sf);
        }
        *(bf16x8*)(xs + off) = xsv;
        *(bf16x8*)(ss + off) = ssv;
    }
}

// ---------------- K2: dual GEMM 128x128, BK=32, counted-vmcnt pipeline ------
// 2 LDS buffers x 4 streams x [128][32] bf16 (8KB) = 64KB -> 2 blocks/CU.
// Swizzle (R8/R10-verified 0-conflict): phys slot = logical ^ ((row>>1)&3).
// Pipeline per step: COMPUTE(cur) ; s_barrier (all waves done reading cur =
// WAR fence) ; STAGE(cur <- tile t+2) ; s_waitcnt vmcnt(8) (tile t+1 landed,
// in-order retire; the 8 just-issued stay IN FLIGHT) ; s_barrier.
__global__ __launch_bounds__(256, 2) void k2_main(
    const unsigned short* __restrict__ xs,   // [T][512] bf16
    const unsigned short* __restrict__ ss,   // [T][512] bf16
    const unsigned short* __restrict__ Wb,   // [512][512] bf16 (OUT x IN)
    const unsigned short* __restrict__ W2b,  // [512][512] bf16
    const float* __restrict__ bias,          // [512]
    float* __restrict__ out)                 // [T][512] fp32
{
    __shared__ unsigned short stg[2][4][128 * 32];   // 64KB
    const int tid  = threadIdx.x;
    const int lane = tid & 63;
    const int w    = tid >> 6;
    const int wr   = w >> 1, wc = w & 1;
    // XCD-chunked bijective swizzle (512 blocks, 64/XCD)
    const int tile = (blockIdx.x & 7) * 64 + (blockIdx.x >> 3);
    const int bm   = tile >> 2;
    const int bn   = tile & 3;

    const int fr = lane & 15;
    const int fs = lane >> 4;

    f32x4 a1[4][4] = {};
    f32x4 a2[4][4] = {};

    const size_t aBase = (size_t)bm * 128 * DIM;
    const size_t bBase = (size_t)bn * 128 * DIM;

    const int srw = lane >> 2;             // row within 16-row issue
    const int sp  = lane & 3;              // phys slot written by this lane

    auto STAGE = [&](int buf, int kb) {
#pragma unroll
        for (int q = 0; q < 2; ++q) {
            int rb   = w * 32 + q * 16;
            int row  = rb + srw;
            int slog = sp ^ ((row >> 1) & 3);   // involutive swizzle
            size_t gA = aBase + (size_t)row * DIM + kb + slog * 8;
            size_t gB = bBase + (size_t)row * DIM + kb + slog * 8;
            __builtin_amdgcn_global_load_lds(
                (__attribute__((address_space(1))) void*)(xs + gA),
                (__attribute__((address_space(3))) void*)(stg[buf][0] + rb * 32), 16, 0, 0);
            __builtin_amdgcn_global_load_lds(
                (__attribute__((address_space(1))) void*)(ss + gA),
                (__attribute__((address_space(3))) void*)(stg[buf][1] + rb * 32), 16, 0, 0);
            __builtin_amdgcn_global_load_lds(
                (__attribute__((address_space(1))) void*)(Wb + gB),
                (__attribute__((address_space(3))) void*)(stg[buf][2] + rb * 32), 16, 0, 0);
            __builtin_amdgcn_global_load_lds(
                (__attribute__((address_space(1))) void*)(W2b + gB),
                (__attribute__((address_space(3))) void*)(stg[buf][3] + rb * 32), 16, 0, 0);
        }
    };

    auto COMPUTE = [&](int buf) {
        bf16x8 axs[4], ass[4], bw[4], bw2[4];
#pragma unroll
        for (int mi = 0; mi < 4; ++mi) {
            int row = wr * 64 + mi * 16 + fr;
            int off = row * 32 + ((fs ^ ((row >> 1) & 3)) * 8);
            axs[mi] = *(const bf16x8*)(stg[buf][0] + off);
            ass[mi] = *(const bf16x8*)(stg[buf][1] + off);
        }
#pragma unroll
        for (int ni = 0; ni < 4; ++ni) {
            int row = wc * 64 + ni * 16 + fr;
            int off = row * 32 + ((fs ^ ((row >> 1) & 3)) * 8);
            bw[ni]  = *(const bf16x8*)(stg[buf][2] + off);
            bw2[ni] = *(const bf16x8*)(stg[buf][3] + off);
        }
#pragma unroll
        for (int mi = 0; mi < 4; ++mi)
#pragma unroll
            for (int ni = 0; ni < 4; ++ni) {
                a1[mi][ni] = __builtin_amdgcn_mfma_f32_16x16x32_bf16(
                    axs[mi], bw[ni], a1[mi][ni], 0, 0, 0);
                a2[mi][ni] = __builtin_amdgcn_mfma_f32_16x16x32_bf16(
                    ass[mi], bw2[ni], a2[mi][ni], 0, 0, 0);
            }
    };

    // prologue: tiles 0 and 1 in flight; wait only for tile 0 (vmcnt(8))
    STAGE(0, 0);
    STAGE(1, 32);
    asm volatile("s_waitcnt vmcnt(8)" ::: "memory");
    __builtin_amdgcn_sched_barrier(0);
    __builtin_amdgcn_s_barrier();

#pragma unroll 1
    for (int t = 0; t < 16; ++t) {
        int cur = t & 1;
        COMPUTE(cur);                        // reads tile t (lgkm consumed by MFMA)
        __builtin_amdgcn_s_barrier();        // all waves done reading buf[cur]
        if (t <= 13) {
            STAGE(cur, (t + 2) * 32);        // overwrite cur with tile t+2 (WAR-safe)
            asm volatile("s_waitcnt vmcnt(8)" ::: "memory");   // tile t+1 landed
        } else if (t == 14) {
            asm volatile("s_waitcnt vmcnt(0)" ::: "memory");   // tile 15 landed
        }
        __builtin_amdgcn_sched_barrier(0);
        __builtin_amdgcn_s_barrier();        // all waves agree next buf ready
    }

    // epilogue: out = a1 * rsqrt(a2 + eps) + bias (direct stores; WRITE ~ideal
    // per R10, 0 conflicts)
#pragma unroll
    for (int ni = 0; ni < 4; ++ni) {
        int o = bn * 128 + wc * 64 + ni * 16 + fr;
        float bo = bias[o];
#pragma unroll
        for (int mi = 0; mi < 4; ++mi) {
#pragma unroll
            for (int j = 0; j < 4; ++j) {
                size_t t = (size_t)bm * 128 + wr * 64 + mi * 16 + fs * 4 + j;
                float d = rsqrtf(a2[mi][ni][j] + 1e-8f);
                out[t * DIM + o] = a1[mi][ni][j] * d + bo;
            }
        }
    }
}

extern "C" void kernel_launch(void* const* d_in, const int* in_sizes, int n_in,
                              void* d_out, int out_size, void* d_ws, size_t ws_size,
                              hipStream_t stream) {
    const float* x      = (const float*)d_in[0];
    const float* mod    = (const float*)d_in[1];
    const float* weight = (const float*)d_in[2];
    const float* bias   = (const float*)d_in[3];
    const float* mod_w  = (const float*)d_in[4];
    const float* mod_b  = (const float*)d_in[5];
    float* out = (float*)d_out;

    char* ws = (char*)d_ws;
    unsigned short* modb = (unsigned short*)(ws);
    unsigned short* xs   = (unsigned short*)(ws + (size_t)16777216);
    unsigned short* ssb  = (unsigned short*)(ws + (size_t)2 * 16777216);
    unsigned short* Wb   = (unsigned short*)(ws + (size_t)3 * 16777216);
    unsigned short* W2b  = (unsigned short*)(ws + (size_t)3 * 16777216 + 524288);
    unsigned short* mwb  = (unsigned short*)(ws + (size_t)3 * 16777216 + 2 * 524288);

    hipLaunchKernelGGL(k0_convert, dim3(2048), dim3(256), 0, stream,
                       mod, weight, mod_w, modb, Wb, W2b, mwb);
    hipLaunchKernelGGL(k1_style, dim3(512), dim3(256), 0, stream,
                       modb, mwb, x, mod_b, xs, ssb);
    hipLaunchKernelGGL(k2_main, dim3(512), dim3(256), 0, stream,
                       xs, ssb, Wb, W2b, bias, out);
}